// Round 2
// baseline (97.336 us; speedup 1.0000x reference)
//
#include <hip/hip_runtime.h>
#include <hip/hip_bf16.h>
#include <math.h>

#define NFEAT 16
#define NRULE 64
#define RSTRIDE 52   // floats per rule block (13 x float4, keeps 16B alignment)

// Packed constant layout per rule r (floats, base = CST + r*RSTRIDE):
//   [0:16)  negc[a]  = -1/(2*sigma^2)
//   [16:32) cmu2[a]  =  mu/sigma^2
//   [32:48) rho_a[a] =  rho[r][a]
//   [48]    bias     =  rho[r][A]
//   [49]    K        = -sum_a mu^2/(2*sigma^2)
//   [50:52) pad
//
// __constant__ (addrspace 4): uniform-address reads compile to s_load_dwordx*
// through the scalar cache -> zero VALU/VMEM cost in the hot loop.
__constant__ float CST[NRULE * RSTRIDE];

__global__ void fuzzy_prep(const float* __restrict__ mu,
                           const float* __restrict__ sigma,
                           const float* __restrict__ rho,
                           float* __restrict__ cst) {
    int r = threadIdx.x;
    if (r >= NRULE) return;
    float* c = cst + r * RSTRIDE;
    float K = 0.0f;
#pragma unroll
    for (int a = 0; a < NFEAT; ++a) {
        float m = mu[r * NFEAT + a];
        float s = sigma[r * NFEAT + a];
        float inv = 1.0f / (2.0f * s * s);
        c[a]      = -inv;
        c[16 + a] = 2.0f * inv * m;
        c[32 + a] = rho[r * (NFEAT + 1) + a];
        K         = fmaf(-inv * m, m, K);
    }
    c[48] = rho[r * (NFEAT + 1) + NFEAT];
    c[49] = K;
    c[50] = 0.0f;
    c[51] = 0.0f;
}

__global__ __launch_bounds__(256) void fuzzy_main(const float* __restrict__ x,
                                                  float* __restrict__ out,
                                                  int n) {
    int k = blockIdx.x * blockDim.x + threadIdx.x;
    if (k >= n) return;

    // Load this sample's 16 features (4 x float4, 64B per thread, coalesced).
    const float4* x4 = (const float4*)(x + (size_t)k * NFEAT);
    float4 v0 = x4[0], v1 = x4[1], v2 = x4[2], v3 = x4[3];
    float xs[NFEAT] = {v0.x, v0.y, v0.z, v0.w,
                       v1.x, v1.y, v1.z, v1.w,
                       v2.x, v2.y, v2.z, v2.w,
                       v3.x, v3.y, v3.z, v3.w};
    float xq[NFEAT];
#pragma unroll
    for (int a = 0; a < NFEAT; ++a) xq[a] = xs[a] * xs[a];

    float num = 0.0f, den = 0.0f;
#pragma unroll 4
    for (int r = 0; r < NRULE; ++r) {
        const float* c = CST + r * RSTRIDE;   // uniform -> s_load (SGPRs)
        float z  = c[48];
        float l0 = c[49];
        float l1 = 0.0f;
#pragma unroll
        for (int a = 0; a < NFEAT; ++a) {
            z  = fmaf(c[32 + a], xs[a], z);
            l0 = fmaf(c[a],      xq[a], l0);
            l1 = fmaf(c[16 + a], xs[a], l1);
        }
        float w = expf(l0 + l1);   // logw <= ~0; underflows to 0 like the ref
        num = fmaf(z, w, num);
        den += w;
    }
    out[k] = num / (den + 1e-13f);
}

extern "C" void kernel_launch(void* const* d_in, const int* in_sizes, int n_in,
                              void* d_out, int out_size, void* d_ws, size_t ws_size,
                              hipStream_t stream) {
    const float* x     = (const float*)d_in[0];   // [N,16]
    const float* mu    = (const float*)d_in[1];   // [64,16]
    const float* sigma = (const float*)d_in[2];   // [64,16]
    const float* rho   = (const float*)d_in[3];   // [64,17]
    float* out = (float*)d_out;

    int n = in_sizes[0] / NFEAT;                  // 131072

    // Resolve the device address of CST and have the prep kernel fill it
    // in-place (sequential dispatches in one stream are acquire/release
    // coherent; the scalar cache is invalidated at dispatch start).
    void* cst_dev = nullptr;
    (void)hipGetSymbolAddress(&cst_dev, HIP_SYMBOL(CST));

    fuzzy_prep<<<1, 64, 0, stream>>>(mu, sigma, rho, (float*)cst_dev);
    fuzzy_main<<<(n + 255) / 256, 256, 0, stream>>>(x, out, n);
}